// Round 5
// baseline (270.637 us; speedup 1.0000x reference)
//
#include <hip/hip_runtime.h>
#include <math.h>

// Problem constants
#define BATCH 32
#define H 512
#define W 512
#define OUT_HW 502          // 512 - 11 + 1
#define TS_X 32             // output tile width
#define TS_Y 22             // output tile height: (22+10) rows * 8 groups = 256 = 1 item/thread
#define RB_ROWS 32          // TS_Y + 10
#define RB_STRIDE 36        // row-blur LDS row stride (floats), mult of 4 (16B align for b128)
#define NTX 16              // 16 * 32 = 512 output cols (>=502)
#define NTY 23              // ceil(502/22)
#define NBLOCKS (NTX * NTY * BATCH)   // 11776
#define N1 ((double)BATCH * H * W)          // MSE denom
#define N2 ((double)BATCH * OUT_HW * OUT_HW) // SSIM denom

struct GaussW { float g[11]; };

// Launch-bounds history (do not re-break this):
//   (256,3) R1: VGPR capped 170 -> spill, 280 MB scratch writes
//   (256,2) R2/R4: VGPR 128, 29-99 MB residual spill (stage-2 2-iteration loop
//                  unrolled -> live set > 128). R5 makes stage A exactly one
//                  item/thread so the live set is ~70 VGPR: no loop, no spill.
//   (256,4) R3: allocator dove to 64 VGPR, 2 GB scratch traffic
__global__ __launch_bounds__(256, 2)
void ssim_tile_kernel(const float* __restrict__ pred,
                      const float* __restrict__ targ,
                      float* __restrict__ ws_contrib,
                      GaussW gw)
{
    __shared__ __align__(16) float rb[5][RB_ROWS * RB_STRIDE];
    __shared__ float red[8];

    const int tid = threadIdx.x;
    const int tx = blockIdx.x, ty = blockIdx.y, b = blockIdx.z;
    const int ox0 = tx * TS_X, oy0 = ty * TS_Y;
    const int rows = min(TS_Y, OUT_HW - oy0);   // valid output rows this tile (>0)
    const int cols = min(TS_X, OUT_HW - ox0);   // valid output cols this tile
    const int rrows = rows + 10;                // h-blurred rows needed (<= 32)
    // MSE ownership must tile the full 512x512 input exactly once:
    // interior tiles own TS_Y input rows; the last y-tile owns through row 511
    // (H - oy0 = 28 = its rrows, so all owned rows are loaded by stage A).
    const int mse_rows = (ty == NTY - 1) ? (H - oy0) : TS_Y;

    const float* __restrict__ pb = pred + (size_t)b * H * W;
    const float* __restrict__ tb = targ + (size_t)b * H * W;

    // ---- Stage A: fused MSE + horizontal blur. Exactly one (row, f4-group)
    // item per thread: r in [0,32), gq in [0,8).
    float mse_local = 0.f;
    {
        const int r = tid >> 3, gq = tid & 7;
        const int c0 = 4 * gq;
        if (r < rrows) {
            const float* prow = pb + (size_t)(oy0 + r) * W;
            const float* trow = tb + (size_t)(oy0 + r) * W;
            float pv[16], tv[16];
            #pragma unroll
            for (int q = 0; q < 4; ++q) {
                int gx = ox0 + c0 + 4 * q;
                float4 vp = make_float4(0.f, 0.f, 0.f, 0.f);
                float4 vt = vp;
                if (gx < W) {                 // gx is 16B-aligned; all-or-nothing
                    vp = *(const float4*)(prow + gx);
                    vt = *(const float4*)(trow + gx);
                }
                *(float4*)(pv + 4 * q) = vp;
                *(float4*)(tv + 4 * q) = vt;
            }

            // MSE over this thread's owned 4 input px (first f4 of its window)
            if (r < mse_rows) {
                #pragma unroll
                for (int j = 0; j < 4; ++j) {
                    float d = pv[j] - tv[j];
                    mse_local = fmaf(d, d, mse_local);
                }
            }

            // 11-tap horizontal blur of 5 channels -> 4 outputs each
            float a[5][4] = {};
            #pragma unroll
            for (int k = 0; k < 11; ++k) {
                float g = gw.g[k];
                #pragma unroll
                for (int j = 0; j < 4; ++j) {
                    float p = pv[j + k], t = tv[j + k];
                    float gp = g * p, gt = g * t;
                    a[0][j] += gp;
                    a[1][j] += gt;
                    a[2][j] = fmaf(gp, p, a[2][j]);
                    a[3][j] = fmaf(gt, t, a[3][j]);
                    a[4][j] = fmaf(gp, t, a[4][j]);
                }
            }
            #pragma unroll
            for (int ch = 0; ch < 5; ++ch) {
                *(float4*)(&rb[ch][r * RB_STRIDE + c0]) =
                    make_float4(a[ch][0], a[ch][1], a[ch][2], a[ch][3]);
            }
        }
    }
    __syncthreads();

    // ---- Stage B: vertical blur, 88 threads, 2 rows x 4 cols each
    float ssim_local = 0.f;
    if (tid < 88) {
        int rg = tid >> 3, gq = tid & 7;
        int r0 = rg * 2, c0 = 4 * gq;
        if (r0 < rows) {
            float acc[5][2][4] = {};   // [ch][row i][col j]
            #pragma unroll
            for (int jr = 0; jr < 12; ++jr) {
                int rr = r0 + jr;
                #pragma unroll
                for (int ch = 0; ch < 5; ++ch) {
                    float4 v = *(const float4*)(&rb[ch][rr * RB_STRIDE + c0]);
                    #pragma unroll
                    for (int i = 0; i < 2; ++i) {
                        int k = jr - i;
                        if (k >= 0 && k < 11) {
                            float g = gw.g[k];
                            acc[ch][i][0] = fmaf(g, v.x, acc[ch][i][0]);
                            acc[ch][i][1] = fmaf(g, v.y, acc[ch][i][1]);
                            acc[ch][i][2] = fmaf(g, v.z, acc[ch][i][2]);
                            acc[ch][i][3] = fmaf(g, v.w, acc[ch][i][3]);
                        }
                    }
                }
            }
            const float C1 = 1e-4f, C2 = 9e-4f;
            #pragma unroll
            for (int i = 0; i < 2; ++i) {
                if (r0 + i < rows) {
                    #pragma unroll
                    for (int j = 0; j < 4; ++j) {
                        if (c0 + j < cols) {
                            float mu1 = acc[0][i][j], mu2 = acc[1][i][j];
                            float xx = acc[2][i][j], yy = acc[3][i][j], xy = acc[4][i][j];
                            float mu1s = mu1 * mu1, mu2s = mu2 * mu2, mu12 = mu1 * mu2;
                            float s1 = xx - mu1s;
                            float s2 = yy - mu2s;
                            float s12 = xy - mu12;
                            float num = (2.f * mu12 + C1) * (2.f * s12 + C2);
                            float den = (mu1s + mu2s + C1) * (s1 + s2 + C2) + 1e-6f;
                            ssim_local += num / den;
                        }
                    }
                }
            }
        }
    }

    // ---- Block reduction (256 threads = 4 waves)
    #pragma unroll
    for (int off = 32; off > 0; off >>= 1) {
        ssim_local += __shfl_down(ssim_local, off, 64);
        mse_local  += __shfl_down(mse_local,  off, 64);
    }
    int wave = tid >> 6;
    if ((tid & 63) == 0) { red[wave] = ssim_local; red[4 + wave] = mse_local; }
    __syncthreads();
    if (tid == 0) {
        float s = red[0] + red[1] + red[2] + red[3];
        float m = red[4] + red[5] + red[6] + red[7];
        // Per-block single-float contribution keeps ws usage at 47 KB
        // (proven-safe <= 64 KB): out = 0.4 + sum(0.6*m/N1 - 0.4*s/N2).
        double contrib = 0.6 * (double)m / N1 - 0.4 * (double)s / N2;
        int bid = (b * NTY + ty) * NTX + tx;
        ws_contrib[bid] = (float)contrib;
    }
}

__global__ __launch_bounds__(1024)
void finalize_kernel(const float* __restrict__ ws_contrib,
                     float* __restrict__ out)
{
    __shared__ double rs[1024];
    int tid = threadIdx.x;
    double s = 0.0;
    for (int i = tid; i < NBLOCKS; i += 1024)
        s += (double)ws_contrib[i];
    rs[tid] = s;
    __syncthreads();
    for (int off = 512; off > 0; off >>= 1) {
        if (tid < off) rs[tid] += rs[tid + off];
        __syncthreads();
    }
    if (tid == 0)
        out[0] = (float)(0.4 + rs[0]);
}

extern "C" void kernel_launch(void* const* d_in, const int* in_sizes, int n_in,
                              void* d_out, int out_size, void* d_ws, size_t ws_size,
                              hipStream_t stream)
{
    const float* pred = (const float*)d_in[0];
    const float* targ = (const float*)d_in[1];
    float* out = (float*)d_out;
    float* ws_contrib = (float*)d_ws;

    // Gaussian taps: computed host-side in double, normalized, passed by value.
    GaussW gw;
    double g[11], sum = 0.0;
    for (int i = 0; i < 11; ++i) { double x = i - 5.0; g[i] = exp(-x * x / 4.5); sum += g[i]; }
    for (int i = 0; i < 11; ++i) gw.g[i] = (float)(g[i] / sum);

    ssim_tile_kernel<<<dim3(NTX, NTY, BATCH), 256, 0, stream>>>(pred, targ, ws_contrib, gw);
    finalize_kernel<<<1, 1024, 0, stream>>>(ws_contrib, out);
}

// Round 6
// 140.751 us; speedup vs baseline: 1.9228x; 1.9228x over previous
//
#include <hip/hip_runtime.h>
#include <math.h>

// Problem constants
#define BATCH 32
#define H 512
#define W 512
#define OUT_HW 502          // 512 - 11 + 1
#define TS_X 32             // output tile width
#define TS_Y 32             // output tile height
#define RB_ROWS 42          // TS_Y + 10
#define RB_STRIDE 36        // row-blur LDS row stride (floats), mult of 4 (16B align)
#define NTX 16              // 512/32
#define NTY 16              // ceil(502/32)
#define NBLOCKS (NTX * NTY * BATCH)   // 8192
#define N1 ((double)BATCH * H * W)           // MSE denom
#define N2 ((double)BATCH * OUT_HW * OUT_HW) // SSIM denom

struct GaussW { float g[11]; };

// Launch-bounds history (do not re-break this):
//   (256,3) R1: VGPR capped 170 -> spill, 280 MB scratch writes
//   (256,4) R3: compiler dove to 64 VGPR, 2 GB scratch traffic
//   (256,2) R2/R4/R5: VGPR 128, no catastrophic spill  <- only sane setting
// The ~30 MB WRITE_SIZE seen in R2/R5 is likely the harness's 0xAA d_ws
// poison being written back from L2 during our dispatch, not spill.
__global__ __launch_bounds__(256, 2)
void ssim_tile_kernel(const float* __restrict__ pred,
                      const float* __restrict__ targ,
                      float* __restrict__ ws_contrib,
                      GaussW gw)
{
    __shared__ __align__(16) float rb[5][RB_ROWS * RB_STRIDE];
    __shared__ float red[8];

    const int tid = threadIdx.x;
    const int tx = blockIdx.x, ty = blockIdx.y, b = blockIdx.z;
    const int ox0 = tx * TS_X, oy0 = ty * TS_Y;
    const int rows = min(TS_Y, OUT_HW - oy0);   // valid output rows (32, or 22 last)
    const int cols = min(TS_X, OUT_HW - ox0);   // valid output cols (32, or 22 last)
    const int rrows = rows + 10;                // h-blurred rows needed (42 / 32)

    const float* __restrict__ pb = pred + (size_t)b * H * W;
    const float* __restrict__ tb = targ + (size_t)b * H * W;

    // ---- Stage A: fused MSE + horizontal blur. Items: rrows x 8 f4-groups
    // (336 interior, 256 last band). unroll 1: keep one item's live set.
    float mse_local = 0.f;
    #pragma unroll 1
    for (int idx = tid; idx < rrows * 8; idx += 256) {
        const int r = idx >> 3, gq = idx & 7;
        const int c0 = 4 * gq;
        const float* prow = pb + (size_t)(oy0 + r) * W;
        const float* trow = tb + (size_t)(oy0 + r) * W;
        float pv[16], tv[16];
        #pragma unroll
        for (int q = 0; q < 4; ++q) {
            int gx = ox0 + c0 + 4 * q;
            float4 vp = make_float4(0.f, 0.f, 0.f, 0.f);
            float4 vt = vp;
            if (gx < W) {                 // 16B-aligned; all-or-nothing
                vp = *(const float4*)(prow + gx);
                vt = *(const float4*)(trow + gx);
            }
            *(float4*)(pv + 4 * q) = vp;
            *(float4*)(tv + 4 * q) = vt;
        }

        // MSE: every tile owns exactly input rows oy0..oy0+31 (last band's
        // rrows is 32, so owned == loaded). Cols: first f4 covers the owned 32.
        if (r < 32) {
            #pragma unroll
            for (int j = 0; j < 4; ++j) {
                float d = pv[j] - tv[j];
                mse_local = fmaf(d, d, mse_local);
            }
        }

        float a[5][4] = {};
        #pragma unroll
        for (int k = 0; k < 11; ++k) {
            float g = gw.g[k];
            #pragma unroll
            for (int j = 0; j < 4; ++j) {
                float p = pv[j + k], t = tv[j + k];
                float gp = g * p, gt = g * t;
                a[0][j] += gp;
                a[1][j] += gt;
                a[2][j] = fmaf(gp, p, a[2][j]);
                a[3][j] = fmaf(gt, t, a[3][j]);
                a[4][j] = fmaf(gp, t, a[4][j]);
            }
        }
        #pragma unroll
        for (int ch = 0; ch < 5; ++ch) {
            *(float4*)(&rb[ch][r * RB_STRIDE + c0]) =
                make_float4(a[ch][0], a[ch][1], a[ch][2], a[ch][3]);
        }
    }
    __syncthreads();

    // ---- Stage B: vertical blur, 2 rows x 2 cols per thread, ALL 256 threads.
    // b64 reads: lanes cover each bank exactly twice per wave (free, m136).
    float ssim_local = 0.f;
    {
        const int rg = tid >> 4, cg = tid & 15;
        const int r0 = 2 * rg, c0 = 2 * cg;
        if (r0 < rows) {
            float acc[5][2][2] = {};   // [ch][row i][col j]
            #pragma unroll
            for (int jr = 0; jr < 12; ++jr) {
                int rr = r0 + jr;
                #pragma unroll
                for (int ch = 0; ch < 5; ++ch) {
                    float2 v = *(const float2*)(&rb[ch][rr * RB_STRIDE + c0]);
                    #pragma unroll
                    for (int i = 0; i < 2; ++i) {
                        int k = jr - i;
                        if (k >= 0 && k < 11) {
                            float g = gw.g[k];
                            acc[ch][i][0] = fmaf(g, v.x, acc[ch][i][0]);
                            acc[ch][i][1] = fmaf(g, v.y, acc[ch][i][1]);
                        }
                    }
                }
            }
            const float C1 = 1e-4f, C2 = 9e-4f;
            #pragma unroll
            for (int i = 0; i < 2; ++i) {
                if (r0 + i < rows) {
                    #pragma unroll
                    for (int j = 0; j < 2; ++j) {
                        if (c0 + j < cols) {
                            float mu1 = acc[0][i][j], mu2 = acc[1][i][j];
                            float xx = acc[2][i][j], yy = acc[3][i][j], xy = acc[4][i][j];
                            float mu1s = mu1 * mu1, mu2s = mu2 * mu2, mu12 = mu1 * mu2;
                            float s1 = xx - mu1s;
                            float s2 = yy - mu2s;
                            float s12 = xy - mu12;
                            float num = (2.f * mu12 + C1) * (2.f * s12 + C2);
                            float den = (mu1s + mu2s + C1) * (s1 + s2 + C2) + 1e-6f;
                            ssim_local += num / den;
                        }
                    }
                }
            }
        }
    }

    // ---- Block reduction (256 threads = 4 waves)
    #pragma unroll
    for (int off = 32; off > 0; off >>= 1) {
        ssim_local += __shfl_down(ssim_local, off, 64);
        mse_local  += __shfl_down(mse_local,  off, 64);
    }
    int wave = tid >> 6;
    if ((tid & 63) == 0) { red[wave] = ssim_local; red[4 + wave] = mse_local; }
    __syncthreads();
    if (tid == 0) {
        float s = red[0] + red[1] + red[2] + red[3];
        float m = red[4] + red[5] + red[6] + red[7];
        double contrib = 0.6 * (double)m / N1 - 0.4 * (double)s / N2;
        int bid = (b * NTY + ty) * NTX + tx;
        ws_contrib[bid] = (float)contrib;
    }
}

__global__ __launch_bounds__(1024)
void finalize_kernel(const float* __restrict__ ws_contrib,
                     float* __restrict__ out)
{
    __shared__ double rs[1024];
    int tid = threadIdx.x;
    double s = 0.0;
    for (int i = tid; i < NBLOCKS; i += 1024)
        s += (double)ws_contrib[i];
    rs[tid] = s;
    __syncthreads();
    for (int off = 512; off > 0; off >>= 1) {
        if (tid < off) rs[tid] += rs[tid + off];
        __syncthreads();
    }
    if (tid == 0)
        out[0] = (float)(0.4 + rs[0]);
}

extern "C" void kernel_launch(void* const* d_in, const int* in_sizes, int n_in,
                              void* d_out, int out_size, void* d_ws, size_t ws_size,
                              hipStream_t stream)
{
    const float* pred = (const float*)d_in[0];
    const float* targ = (const float*)d_in[1];
    float* out = (float*)d_out;
    float* ws_contrib = (float*)d_ws;

    // Gaussian taps: computed host-side in double, normalized, passed by value.
    GaussW gw;
    double g[11], sum = 0.0;
    for (int i = 0; i < 11; ++i) { double x = i - 5.0; g[i] = exp(-x * x / 4.5); sum += g[i]; }
    for (int i = 0; i < 11; ++i) gw.g[i] = (float)(g[i] / sum);

    ssim_tile_kernel<<<dim3(NTX, NTY, BATCH), 256, 0, stream>>>(pred, targ, ws_contrib, gw);
    finalize_kernel<<<1, 1024, 0, stream>>>(ws_contrib, out);
}

// Round 7
// 134.990 us; speedup vs baseline: 2.0049x; 1.0427x over previous
//
#include <hip/hip_runtime.h>
#include <math.h>

// Problem constants
#define BATCH 32
#define H 512
#define W 512
#define OUT_HW 502          // 512 - 11 + 1
#define TS_X 32             // output tile width
#define TS_Y 32             // output tile height
#define RB_ROWS 42          // TS_Y + 10
#define RB_STRIDE 36        // row-blur LDS row stride (floats), mult of 4 (16B align)
#define NTX 16              // 512/32
#define NTY 16              // ceil(502/32)
#define NBLOCKS (NTX * NTY * BATCH)   // 8192
#define N1 ((double)BATCH * H * W)           // MSE denom
#define N2 ((double)BATCH * OUT_HW * OUT_HW) // SSIM denom

struct GaussW { float g[11]; };

// Launch-bounds history (do not re-break this):
//   (256,3) R1: VGPR capped 170 -> spill, 280 MB scratch writes
//   (256,4) R3: compiler dove to 64 VGPR, 2 GB scratch traffic
//   (256,2) R2..R6: sane. R6: VGPR 84, WRITE_SIZE 256 B (no spill).
//
// R7: (s,d) transform. s=p+t, d=p-t; blur {s, d, s^2, d^2} (4 channels
// instead of 5). A=mu1+mu2, B=mu1-mu2, U=blur(s^2), V=blur(d^2):
//   2*mu1*mu2   = (A^2-B^2)/2      mu1^2+mu2^2 = (A^2+B^2)/2
//   2*sigma12   = (U-V)/2 - 2mu1mu2
//   sig1^2+sig2^2 = (U+V)/2 - (mu1^2+mu2^2)
// MSE is sum of d^2 = dd channel directly.
__global__ __launch_bounds__(256, 2)
void ssim_tile_kernel(const float* __restrict__ pred,
                      const float* __restrict__ targ,
                      float* __restrict__ ws_contrib,
                      GaussW gw)
{
    __shared__ __align__(16) float rb[4][RB_ROWS * RB_STRIDE];
    __shared__ float red[8];

    const int tid = threadIdx.x;
    const int tx = blockIdx.x, ty = blockIdx.y, b = blockIdx.z;
    const int ox0 = tx * TS_X, oy0 = ty * TS_Y;
    const int rows = min(TS_Y, OUT_HW - oy0);   // valid output rows (32, or 22 last)
    const int cols = min(TS_X, OUT_HW - ox0);   // valid output cols (32, or 22 last)
    const int rrows = rows + 10;                // h-blurred rows needed (42 / 32)

    const float* __restrict__ pb = pred + (size_t)b * H * W;
    const float* __restrict__ tb = targ + (size_t)b * H * W;

    // ---- Stage A: fused MSE + horizontal blur of {s, d, s^2, d^2}.
    float mse_local = 0.f;
    #pragma unroll 1
    for (int idx = tid; idx < rrows * 8; idx += 256) {
        const int r = idx >> 3, gq = idx & 7;
        const int c0 = 4 * gq;
        const float* prow = pb + (size_t)(oy0 + r) * W;
        const float* trow = tb + (size_t)(oy0 + r) * W;
        float sv[16], dv[16], ss[16], dd[16];
        #pragma unroll
        for (int q = 0; q < 4; ++q) {
            int gx = ox0 + c0 + 4 * q;
            float4 vp = make_float4(0.f, 0.f, 0.f, 0.f);
            float4 vt = vp;
            if (gx < W) {                 // 16B-aligned; all-or-nothing
                vp = *(const float4*)(prow + gx);
                vt = *(const float4*)(trow + gx);
            }
            *(float4*)(sv + 4 * q) = vp;  // temporarily p
            *(float4*)(dv + 4 * q) = vt;  // temporarily t
        }
        #pragma unroll
        for (int i = 0; i < 16; ++i) {
            float p = sv[i], t = dv[i];
            float s = p + t, d = p - t;
            sv[i] = s; dv[i] = d;
            ss[i] = s * s; dd[i] = d * d;
        }

        // MSE: every tile owns exactly input rows oy0..oy0+31; first f4 = owned cols.
        if (r < 32)
            mse_local += dd[0] + dd[1] + dd[2] + dd[3];

        float a[4][4] = {};
        #pragma unroll
        for (int k = 0; k < 11; ++k) {
            float g = gw.g[k];
            #pragma unroll
            for (int j = 0; j < 4; ++j) {
                a[0][j] = fmaf(g, sv[j + k], a[0][j]);
                a[1][j] = fmaf(g, dv[j + k], a[1][j]);
                a[2][j] = fmaf(g, ss[j + k], a[2][j]);
                a[3][j] = fmaf(g, dd[j + k], a[3][j]);
            }
        }
        #pragma unroll
        for (int ch = 0; ch < 4; ++ch) {
            *(float4*)(&rb[ch][r * RB_STRIDE + c0]) =
                make_float4(a[ch][0], a[ch][1], a[ch][2], a[ch][3]);
        }
    }
    __syncthreads();

    // ---- Stage B: vertical blur, 2 rows x 2 cols per thread, ALL 256 threads.
    float ssim_local = 0.f;
    {
        const int rg = tid >> 4, cg = tid & 15;
        const int r0 = 2 * rg, c0 = 2 * cg;
        if (r0 < rows) {
            float acc[4][2][2] = {};   // [ch][row i][col j]
            #pragma unroll
            for (int jr = 0; jr < 12; ++jr) {
                int rr = r0 + jr;
                #pragma unroll
                for (int ch = 0; ch < 4; ++ch) {
                    float2 v = *(const float2*)(&rb[ch][rr * RB_STRIDE + c0]);
                    #pragma unroll
                    for (int i = 0; i < 2; ++i) {
                        int k = jr - i;
                        if (k >= 0 && k < 11) {
                            float g = gw.g[k];
                            acc[ch][i][0] = fmaf(g, v.x, acc[ch][i][0]);
                            acc[ch][i][1] = fmaf(g, v.y, acc[ch][i][1]);
                        }
                    }
                }
            }
            const float C1 = 1e-4f, C2 = 9e-4f;
            #pragma unroll
            for (int i = 0; i < 2; ++i) {
                if (r0 + i < rows) {
                    #pragma unroll
                    for (int j = 0; j < 2; ++j) {
                        if (c0 + j < cols) {
                            float A  = acc[0][i][j], Bv = acc[1][i][j];
                            float U  = acc[2][i][j], V  = acc[3][i][j];
                            float A2 = A * A, B2 = Bv * Bv;
                            float mu12_2 = 0.5f * (A2 - B2);      // 2*mu1*mu2
                            float musq   = 0.5f * (A2 + B2);      // mu1^2+mu2^2
                            float sig12_2 = 0.5f * (U - V) - mu12_2;
                            float sigsum  = 0.5f * (U + V) - musq;
                            float num = (mu12_2 + C1) * (sig12_2 + C2);
                            float den = (musq + C1) * (sigsum + C2) + 1e-6f;
                            ssim_local += num / den;
                        }
                    }
                }
            }
        }
    }

    // ---- Block reduction (256 threads = 4 waves)
    #pragma unroll
    for (int off = 32; off > 0; off >>= 1) {
        ssim_local += __shfl_down(ssim_local, off, 64);
        mse_local  += __shfl_down(mse_local,  off, 64);
    }
    int wave = tid >> 6;
    if ((tid & 63) == 0) { red[wave] = ssim_local; red[4 + wave] = mse_local; }
    __syncthreads();
    if (tid == 0) {
        float s = red[0] + red[1] + red[2] + red[3];
        float m = red[4] + red[5] + red[6] + red[7];
        double contrib = 0.6 * (double)m / N1 - 0.4 * (double)s / N2;
        int bid = (b * NTY + ty) * NTX + tx;
        ws_contrib[bid] = (float)contrib;
    }
}

__global__ __launch_bounds__(1024)
void finalize_kernel(const float* __restrict__ ws_contrib,
                     float* __restrict__ out)
{
    __shared__ double rs[1024];
    int tid = threadIdx.x;
    double s = 0.0;
    for (int i = tid; i < NBLOCKS; i += 1024)
        s += (double)ws_contrib[i];
    rs[tid] = s;
    __syncthreads();
    for (int off = 512; off > 0; off >>= 1) {
        if (tid < off) rs[tid] += rs[tid + off];
        __syncthreads();
    }
    if (tid == 0)
        out[0] = (float)(0.4 + rs[0]);
}

extern "C" void kernel_launch(void* const* d_in, const int* in_sizes, int n_in,
                              void* d_out, int out_size, void* d_ws, size_t ws_size,
                              hipStream_t stream)
{
    const float* pred = (const float*)d_in[0];
    const float* targ = (const float*)d_in[1];
    float* out = (float*)d_out;
    float* ws_contrib = (float*)d_ws;

    // Gaussian taps: computed host-side in double, normalized, passed by value.
    GaussW gw;
    double g[11], sum = 0.0;
    for (int i = 0; i < 11; ++i) { double x = i - 5.0; g[i] = exp(-x * x / 4.5); sum += g[i]; }
    for (int i = 0; i < 11; ++i) gw.g[i] = (float)(g[i] / sum);

    ssim_tile_kernel<<<dim3(NTX, NTY, BATCH), 256, 0, stream>>>(pred, targ, ws_contrib, gw);
    finalize_kernel<<<1, 1024, 0, stream>>>(ws_contrib, out);
}

// Round 8
// 122.846 us; speedup vs baseline: 2.2031x; 1.0989x over previous
//
#include <hip/hip_runtime.h>
#include <math.h>

// Problem constants
#define BATCH 32
#define H 512
#define W 512
#define OUT_HW 502          // 512 - 11 + 1
#define TS_X 32             // output strip width
#define BAND 32             // output rows per band
#define NBANDS 8
#define STRIP (BAND * NBANDS)   // 256 output rows per block
#define RB_ROWS 42          // band window: 32 outputs + 10 halo
#define RB_STRIDE 36        // LDS row stride (floats): 32 data + 4 pad (bank spread)
#define NTX 16              // 512/32 column strips
#define NSTRIP 2            // 2 row strips of 256
#define NBLOCKS (NTX * NSTRIP * BATCH)   // 1024
#define N1 ((double)BATCH * H * W)            // MSE denom
#define N2 ((double)BATCH * OUT_HW * OUT_HW)  // SSIM denom

struct GaussW { float g[11]; };

// Launch-bounds history (do not re-break this):
//   (256,3) R1: VGPR capped 170 -> spill disaster; (256,4) R3: 64-VGPR dive, 2 GB scratch
//   (256,2) R2..R7: sane. R7: VGPR 52, WRITE_SIZE 256 B.
// R8: sliding-window strips. Each block: 32-wide x 256-tall outputs, 8 bands
// of 32 rows. Between bands the 10-row h-blurred halo is copied down in LDS
// (10 rows x 4ch) instead of recomputed: h-blur rows per 256 outputs
// 336 -> 266 (-21% stage-A work). (s,d) channel transform as R7.
__global__ __launch_bounds__(256, 2)
void ssim_strip_kernel(const float* __restrict__ pred,
                       const float* __restrict__ targ,
                       float* __restrict__ ws_contrib,
                       GaussW gw)
{
    __shared__ __align__(16) float rb[4][RB_ROWS * RB_STRIDE];
    __shared__ float red[8];

    const int tid = threadIdx.x;
    const int tx = blockIdx.x, sy = blockIdx.y, b = blockIdx.z;
    const int ox0 = tx * TS_X;
    const int S = sy * STRIP;                    // first output/input row of strip
    const int cols = min(TS_X, OUT_HW - ox0);    // valid output cols (32, or 22 for tx=15)
    const int mse_end = S + STRIP;               // strip owns input rows [S, S+256)
    const bool interior_x = (ox0 + 44 <= W);     // all 16-px windows in-bounds (tx<=14)

    const float* __restrict__ pb = pred + (size_t)b * H * W;
    const float* __restrict__ tb = targ + (size_t)b * H * W;

    // Stage-B per-thread constants (2 rows x 2 cols per thread, 256 items/band)
    const int br0 = 2 * (tid >> 4);
    const int bc0 = 2 * (tid & 15);

    float mse_local = 0.f, ssim_local = 0.f;

    #pragma unroll 1
    for (int band = 0; band < NBANDS; ++band) {
        const int out0  = S + band * BAND;             // first output row of band
        const int brows = min(BAND, OUT_HW - out0);    // 32, or 22 (last band, last strip)
        const int h0    = (band == 0) ? S : (out0 + 10); // first NEW h-blur row
        const int h1    = min(out0 + brows + 10, H);     // end of new h-rows
        const int nnew  = h1 - h0;                       // 42 / 32 / 22
        const int slot0 = h0 - out0;                     // LDS slot of first new row (0 or 10)

        if (band > 0) {
            __syncthreads();            // previous stage B done reading
            // copy-down: slots 32..41 (rows out0..out0+9) -> slots 0..9
            if (tid < 80) {
                const int r = tid >> 3, q = (tid & 7) * 4;
                const int src = (32 + r) * RB_STRIDE + q;
                const int dst = r * RB_STRIDE + q;
                float4 v0 = *(const float4*)&rb[0][src];
                float4 v1 = *(const float4*)&rb[1][src];
                float4 v2 = *(const float4*)&rb[2][src];
                float4 v3 = *(const float4*)&rb[3][src];
                *(float4*)&rb[0][dst] = v0;
                *(float4*)&rb[1][dst] = v1;
                *(float4*)&rb[2][dst] = v2;
                *(float4*)&rb[3][dst] = v3;
            }
            __syncthreads();            // copy visible before stage A overwrites 10..41
        }

        // ---- Stage A: h-blur the nnew new rows into slots slot0..slot0+nnew-1
        #pragma unroll 1
        for (int idx = tid; idx < nnew * 8; idx += 256) {
            const int r = idx >> 3, gq = idx & 7;
            const int c0 = 4 * gq;
            const int gy = h0 + r;                      // < H by construction
            const float* prow = pb + ((size_t)gy << 9) + ox0 + c0;
            const float* trow = tb + ((size_t)gy << 9) + ox0 + c0;
            float sv[16], dv[16], ss[16], dd[16];
            if (interior_x) {           // block-uniform branch: no divergence
                #pragma unroll
                for (int q = 0; q < 4; ++q) {
                    *(float4*)(sv + 4 * q) = *(const float4*)(prow + 4 * q);
                    *(float4*)(dv + 4 * q) = *(const float4*)(trow + 4 * q);
                }
            } else {
                #pragma unroll
                for (int q = 0; q < 4; ++q) {
                    int gx = ox0 + c0 + 4 * q;
                    float4 vp = make_float4(0.f, 0.f, 0.f, 0.f);
                    float4 vt = vp;
                    if (gx < W) {       // 16B-aligned: all-or-nothing
                        vp = *(const float4*)(prow + 4 * q);
                        vt = *(const float4*)(trow + 4 * q);
                    }
                    *(float4*)(sv + 4 * q) = vp;
                    *(float4*)(dv + 4 * q) = vt;
                }
            }
            #pragma unroll
            for (int i = 0; i < 16; ++i) {
                float p = sv[i], t = dv[i];
                float s = p + t, d = p - t;
                sv[i] = s; dv[i] = d;
                ss[i] = s * s; dd[i] = d * d;
            }

            // MSE: strip owns input rows [S, S+256); each h-row processed once.
            // First f4 (cols ox0+c0..+3) = exact x-cover across the 8 groups.
            if (gy < mse_end)
                mse_local += dd[0] + dd[1] + dd[2] + dd[3];

            float a[4][4] = {};
            #pragma unroll
            for (int k = 0; k < 11; ++k) {
                float g = gw.g[k];
                #pragma unroll
                for (int j = 0; j < 4; ++j) {
                    a[0][j] = fmaf(g, sv[j + k], a[0][j]);
                    a[1][j] = fmaf(g, dv[j + k], a[1][j]);
                    a[2][j] = fmaf(g, ss[j + k], a[2][j]);
                    a[3][j] = fmaf(g, dd[j + k], a[3][j]);
                }
            }
            const int wr = (slot0 + r) * RB_STRIDE + c0;
            #pragma unroll
            for (int ch = 0; ch < 4; ++ch)
                *(float4*)(&rb[ch][wr]) = make_float4(a[ch][0], a[ch][1], a[ch][2], a[ch][3]);
        }
        __syncthreads();

        // ---- Stage B: vertical blur, 2 rows x 2 cols per thread (slots 0..41)
        if (br0 < brows) {
            float acc[4][2][2] = {};   // [ch][row i][col j]
            #pragma unroll
            for (int jr = 0; jr < 12; ++jr) {
                int rr = br0 + jr;
                #pragma unroll
                for (int ch = 0; ch < 4; ++ch) {
                    float2 v = *(const float2*)(&rb[ch][rr * RB_STRIDE + bc0]);
                    #pragma unroll
                    for (int i = 0; i < 2; ++i) {
                        int k = jr - i;
                        if (k >= 0 && k < 11) {
                            float g = gw.g[k];
                            acc[ch][i][0] = fmaf(g, v.x, acc[ch][i][0]);
                            acc[ch][i][1] = fmaf(g, v.y, acc[ch][i][1]);
                        }
                    }
                }
            }
            const float C1 = 1e-4f, C2 = 9e-4f;
            #pragma unroll
            for (int i = 0; i < 2; ++i) {
                if (br0 + i < brows) {
                    #pragma unroll
                    for (int j = 0; j < 2; ++j) {
                        if (bc0 + j < cols) {
                            float A  = acc[0][i][j], Bv = acc[1][i][j];
                            float U  = acc[2][i][j], V  = acc[3][i][j];
                            float A2 = A * A, B2 = Bv * Bv;
                            float mu12_2 = 0.5f * (A2 - B2);      // 2*mu1*mu2
                            float musq   = 0.5f * (A2 + B2);      // mu1^2+mu2^2
                            float sig12_2 = 0.5f * (U - V) - mu12_2;
                            float sigsum  = 0.5f * (U + V) - musq;
                            float num = (mu12_2 + C1) * (sig12_2 + C2);
                            float den = (musq + C1) * (sigsum + C2) + 1e-6f;
                            ssim_local += num / den;
                        }
                    }
                }
            }
        }
        // WAR hazard vs next band's copy/A handled by loop-top barrier
    }

    // ---- Block reduction (once per block; 256 threads = 4 waves)
    #pragma unroll
    for (int off = 32; off > 0; off >>= 1) {
        ssim_local += __shfl_down(ssim_local, off, 64);
        mse_local  += __shfl_down(mse_local,  off, 64);
    }
    int wave = tid >> 6;
    if ((tid & 63) == 0) { red[wave] = ssim_local; red[4 + wave] = mse_local; }
    __syncthreads();
    if (tid == 0) {
        float s = red[0] + red[1] + red[2] + red[3];
        float m = red[4] + red[5] + red[6] + red[7];
        double contrib = 0.6 * (double)m / N1 - 0.4 * (double)s / N2;
        int bid = (b * NSTRIP + sy) * NTX + tx;
        ws_contrib[bid] = (float)contrib;
    }
}

__global__ __launch_bounds__(1024)
void finalize_kernel(const float* __restrict__ ws_contrib,
                     float* __restrict__ out)
{
    __shared__ double rs[1024];
    int tid = threadIdx.x;
    double s = 0.0;
    for (int i = tid; i < NBLOCKS; i += 1024)
        s += (double)ws_contrib[i];
    rs[tid] = s;
    __syncthreads();
    for (int off = 512; off > 0; off >>= 1) {
        if (tid < off) rs[tid] += rs[tid + off];
        __syncthreads();
    }
    if (tid == 0)
        out[0] = (float)(0.4 + rs[0]);
}

extern "C" void kernel_launch(void* const* d_in, const int* in_sizes, int n_in,
                              void* d_out, int out_size, void* d_ws, size_t ws_size,
                              hipStream_t stream)
{
    const float* pred = (const float*)d_in[0];
    const float* targ = (const float*)d_in[1];
    float* out = (float*)d_out;
    float* ws_contrib = (float*)d_ws;

    // Gaussian taps: computed host-side in double, normalized, passed by value.
    GaussW gw;
    double g[11], sum = 0.0;
    for (int i = 0; i < 11; ++i) { double x = i - 5.0; g[i] = exp(-x * x / 4.5); sum += g[i]; }
    for (int i = 0; i < 11; ++i) gw.g[i] = (float)(g[i] / sum);

    ssim_strip_kernel<<<dim3(NTX, NSTRIP, BATCH), 256, 0, stream>>>(pred, targ, ws_contrib, gw);
    finalize_kernel<<<1, 1024, 0, stream>>>(ws_contrib, out);
}